// Round 8
// baseline (185.333 us; speedup 1.0000x reference)
//
#include <hip/hip_runtime.h>
#include <hip/hip_bf16.h>

#define S_LEN 512
#define EMB   512
#define NHEAD 8
#define DPH   64
#define NREL  3
#define BATCH 8

typedef __attribute__((ext_vector_type(8))) short bf16x8;
typedef __attribute__((ext_vector_type(4))) float f32x4;

__device__ __forceinline__ float bf2f(unsigned short u) {
    union { unsigned int i; float f; } cv;
    cv.i = ((unsigned int)u) << 16;
    return cv.f;
}
__device__ __forceinline__ unsigned short f2bf(float f) {
    __hip_bfloat16 h = __float2bfloat16(f);
    return *reinterpret_cast<unsigned short*>(&h);
}

// ---------------------------------------------------------------------------
// Weight transpose: Wt[z][n][k] (bf16) = W[z][k][n] (f32), z in {q,k,v,o}.
// ---------------------------------------------------------------------------
__global__ __launch_bounds__(256) void transpose_w(
    const float* __restrict__ Wq, const float* __restrict__ Wk,
    const float* __restrict__ Wv, const float* __restrict__ Wo,
    unsigned short* __restrict__ Wt)
{
    const int z = blockIdx.z;
    const float* W = (z == 0) ? Wq : (z == 1) ? Wk : (z == 2) ? Wv : Wo;
    unsigned short* dst = Wt + (size_t)z * EMB * EMB;

    __shared__ float tile[64][65];
    const int n0 = blockIdx.x * 64, k0 = blockIdx.y * 64;
    const int t = threadIdx.x;
    const int cr = t >> 4, cc = (t & 15) * 4;

    #pragma unroll
    for (int it = 0; it < 4; ++it) {
        int r = cr + it * 16;
        float4 v = *reinterpret_cast<const float4*>(W + (size_t)(k0 + r) * EMB + n0 + cc);
        tile[r][cc + 0] = v.x; tile[r][cc + 1] = v.y;
        tile[r][cc + 2] = v.z; tile[r][cc + 3] = v.w;
    }
    __syncthreads();
    #pragma unroll
    for (int it = 0; it < 4; ++it) {
        int n = cr + it * 16;
        ushort4 o;
        o.x = f2bf(tile[cc + 0][n]); o.y = f2bf(tile[cc + 1][n]);
        o.z = f2bf(tile[cc + 2][n]); o.w = f2bf(tile[cc + 3][n]);
        *reinterpret_cast<ushort4*>(dst + (size_t)(n0 + n) * EMB + k0 + cc) = o;
    }
}

// ---------------------------------------------------------------------------
// MFMA projection GEMM. 128x64 tile, 4 waves 2x2.
// z==2 (V) writes TRANSPOSED per-head: vbT[(b*NHEAD+h)*DPH + d][s] (bf16),
// so attention can stage V^T with linear loads. q/k write [s][e] as before.
// ---------------------------------------------------------------------------
__global__ __launch_bounds__(256) void gemm_proj_mfma(
    const float* __restrict__ Aq, const float* __restrict__ Ak, const float* __restrict__ Av,
    const unsigned short* __restrict__ Wt,
    const float* __restrict__ bqp, const float* __restrict__ bkp, const float* __restrict__ bvp,
    unsigned short* __restrict__ oq, unsigned short* __restrict__ okp, unsigned short* __restrict__ ov)
{
    const int z = blockIdx.z;
    const float* A = (z == 0) ? Aq : (z == 1) ? Ak : Av;
    const unsigned short* W = Wt + (size_t)z * EMB * EMB;
    const float* bias = (z == 0) ? bqp : (z == 1) ? bkp : bvp;
    unsigned short* out = (z == 0) ? oq : (z == 1) ? okp : ov;

    const int n0 = blockIdx.x * 64;
    const int m0 = blockIdx.y * 128;
    const int tid = threadIdx.x;
    const int lane = tid & 63;
    const int wid = tid >> 6;
    const int wr = wid >> 1, wc = wid & 1;

    __shared__ __align__(16) unsigned char smA[128 * 64 * 2];
    __shared__ __align__(16) unsigned char smB[64 * 64 * 2];

    f32x4 acc[4][2] = {};

    for (int k0 = 0; k0 < EMB; k0 += 64) {
        __syncthreads();
        #pragma unroll
        for (int it = 0; it < 4; ++it) {
            int w = it * 256 + tid;
            int row = w >> 3, kc = w & 7;
            const float* src = A + (size_t)(m0 + row) * EMB + k0 + kc * 8;
            float4 v0 = *reinterpret_cast<const float4*>(src);
            float4 v1 = *reinterpret_cast<const float4*>(src + 4);
            union { unsigned short s[8]; uint4 u; } p;
            p.s[0] = f2bf(v0.x); p.s[1] = f2bf(v0.y); p.s[2] = f2bf(v0.z); p.s[3] = f2bf(v0.w);
            p.s[4] = f2bf(v1.x); p.s[5] = f2bf(v1.y); p.s[6] = f2bf(v1.z); p.s[7] = f2bf(v1.w);
            unsigned byte = ((unsigned)row << 7) + ((unsigned)kc << 4);
            byte ^= (unsigned)((row & 7) << 4);
            *reinterpret_cast<uint4*>(smA + byte) = p.u;
        }
        #pragma unroll
        for (int it = 0; it < 2; ++it) {
            int w = it * 256 + tid;
            int row = w >> 3, kc = w & 7;
            uint4 raw = *reinterpret_cast<const uint4*>(W + (size_t)(n0 + row) * EMB + k0 + kc * 8);
            unsigned byte = ((unsigned)row << 7) + ((unsigned)kc << 4);
            byte ^= (unsigned)((row & 7) << 4);
            *reinterpret_cast<uint4*>(smB + byte) = raw;
        }
        __syncthreads();

        #pragma unroll
        for (int ks = 0; ks < 2; ++ks) {
            bf16x8 bfrag[2];
            #pragma unroll
            for (int ni = 0; ni < 2; ++ni) {
                int col = wc * 32 + ni * 16 + (lane & 15);
                unsigned byte = ((unsigned)col << 7) + (unsigned)(ks << 6) + (unsigned)((lane >> 4) << 4);
                byte ^= (unsigned)((col & 7) << 4);
                bfrag[ni] = *reinterpret_cast<const bf16x8*>(smB + byte);
            }
            #pragma unroll
            for (int mi = 0; mi < 4; ++mi) {
                int row = wr * 64 + mi * 16 + (lane & 15);
                unsigned byte = ((unsigned)row << 7) + (unsigned)(ks << 6) + (unsigned)((lane >> 4) << 4);
                byte ^= (unsigned)((row & 7) << 4);
                bf16x8 afrag = *reinterpret_cast<const bf16x8*>(smA + byte);
                #pragma unroll
                for (int ni = 0; ni < 2; ++ni)
                    acc[mi][ni] = __builtin_amdgcn_mfma_f32_16x16x32_bf16(afrag, bfrag[ni], acc[mi][ni], 0, 0, 0);
            }
        }
    }

    if (z == 2) {
        // transposed per-head store: one ushort4 (4 consecutive s) per (mi,ni)
        #pragma unroll
        for (int ni = 0; ni < 2; ++ni) {
            int colg = n0 + wc * 32 + ni * 16 + (lane & 15);
            float bj = bias[colg];
            int hh = colg >> 6, dd = colg & 63;
            #pragma unroll
            for (int mi = 0; mi < 4; ++mi) {
                int rbase = m0 + wr * 64 + mi * 16 + ((lane >> 4) << 2);
                int bb = rbase >> 9, ss = rbase & 511;
                ushort4 o;
                o.x = f2bf(acc[mi][ni][0] + bj);
                o.y = f2bf(acc[mi][ni][1] + bj);
                o.z = f2bf(acc[mi][ni][2] + bj);
                o.w = f2bf(acc[mi][ni][3] + bj);
                *reinterpret_cast<ushort4*>(out + ((size_t)(bb * NHEAD + hh) * DPH + dd) * S_LEN + ss) = o;
            }
        }
    } else {
        #pragma unroll
        for (int ni = 0; ni < 2; ++ni) {
            int colg = n0 + wc * 32 + ni * 16 + (lane & 15);
            float bj = bias[colg];
            #pragma unroll
            for (int mi = 0; mi < 4; ++mi) {
                int rbase = m0 + wr * 64 + mi * 16 + ((lane >> 4) << 2);
                #pragma unroll
                for (int q = 0; q < 4; ++q)
                    out[(size_t)(rbase + q) * EMB + colg] = f2bf(acc[mi][ni][q] + bj);
            }
        }
    }
}

// ---------------------------------------------------------------------------
// MFMA output GEMM (validated round 5).
// ---------------------------------------------------------------------------
__global__ __launch_bounds__(256) void gemm_out_mfma(
    const unsigned short* __restrict__ A,
    const unsigned short* __restrict__ W,
    const float* __restrict__ bias,
    float* __restrict__ out)
{
    const int n0 = blockIdx.x * 64;
    const int m0 = blockIdx.y * 128;
    const int tid = threadIdx.x;
    const int lane = tid & 63;
    const int wid = tid >> 6;
    const int wr = wid >> 1, wc = wid & 1;

    __shared__ __align__(16) unsigned char smA[128 * 64 * 2];
    __shared__ __align__(16) unsigned char smB[64 * 64 * 2];

    f32x4 acc[4][2] = {};

    for (int k0 = 0; k0 < EMB; k0 += 64) {
        __syncthreads();
        #pragma unroll
        for (int it = 0; it < 4; ++it) {
            int w = it * 256 + tid;
            int row = w >> 3, kc = w & 7;
            uint4 raw = *reinterpret_cast<const uint4*>(A + (size_t)(m0 + row) * EMB + k0 + kc * 8);
            unsigned byte = ((unsigned)row << 7) + ((unsigned)kc << 4);
            byte ^= (unsigned)((row & 7) << 4);
            *reinterpret_cast<uint4*>(smA + byte) = raw;
        }
        #pragma unroll
        for (int it = 0; it < 2; ++it) {
            int w = it * 256 + tid;
            int row = w >> 3, kc = w & 7;
            uint4 raw = *reinterpret_cast<const uint4*>(W + (size_t)(n0 + row) * EMB + k0 + kc * 8);
            unsigned byte = ((unsigned)row << 7) + ((unsigned)kc << 4);
            byte ^= (unsigned)((row & 7) << 4);
            *reinterpret_cast<uint4*>(smB + byte) = raw;
        }
        __syncthreads();

        #pragma unroll
        for (int ks = 0; ks < 2; ++ks) {
            bf16x8 bfrag[2];
            #pragma unroll
            for (int ni = 0; ni < 2; ++ni) {
                int col = wc * 32 + ni * 16 + (lane & 15);
                unsigned byte = ((unsigned)col << 7) + (unsigned)(ks << 6) + (unsigned)((lane >> 4) << 4);
                byte ^= (unsigned)((col & 7) << 4);
                bfrag[ni] = *reinterpret_cast<const bf16x8*>(smB + byte);
            }
            #pragma unroll
            for (int mi = 0; mi < 4; ++mi) {
                int row = wr * 64 + mi * 16 + (lane & 15);
                unsigned byte = ((unsigned)row << 7) + (unsigned)(ks << 6) + (unsigned)((lane >> 4) << 4);
                byte ^= (unsigned)((row & 7) << 4);
                bf16x8 afrag = *reinterpret_cast<const bf16x8*>(smA + byte);
                #pragma unroll
                for (int ni = 0; ni < 2; ++ni)
                    acc[mi][ni] = __builtin_amdgcn_mfma_f32_16x16x32_bf16(afrag, bfrag[ni], acc[mi][ni], 0, 0, 0);
            }
        }
    }

    #pragma unroll
    for (int ni = 0; ni < 2; ++ni) {
        int colg = n0 + wc * 32 + ni * 16 + (lane & 15);
        float bj = bias[colg];
        #pragma unroll
        for (int mi = 0; mi < 4; ++mi) {
            int rbase = m0 + wr * 64 + mi * 16 + ((lane >> 4) << 2);
            #pragma unroll
            for (int q = 0; q < 4; ++q)
                out[(size_t)(rbase + q) * EMB + colg] = acc[mi][ni][q] + bj;
        }
    }
}

// ---------------------------------------------------------------------------
// MFMA relation-aware flash attention, v2:
//  - K and V^T double-buffered in LDS, ONE barrier per tile
//  - ordering: write(tt)->barrier->issue loads(tt+1)->compute(tt)
//    (loads overlap compute; waited only at next tile's ds_write)
//  - V^T staged linearly from vbT (no 16-way scatter)
//  - rel indices prefetched one tile ahead into registers
//  - qrel hoisted to 3 registers per lane
// ---------------------------------------------------------------------------
__global__ __launch_bounds__(256) void attn_mfma(
    const unsigned short* __restrict__ qb,
    const unsigned short* __restrict__ kb,
    const unsigned short* __restrict__ vbT,
    const int* __restrict__ rel,
    const float* __restrict__ rel_k, const float* __restrict__ rel_v,
    unsigned short* __restrict__ ob)
{
    const int s0 = blockIdx.x * 64;
    const int h  = blockIdx.y;
    const int b  = blockIdx.z;
    const int tid = threadIdx.x;
    const int lane = tid & 63;
    const int wid = tid >> 6;
    const int sl = lane & 15;
    const int tg = lane >> 4;

    __shared__ __align__(16) unsigned char smQ[64 * 128];
    __shared__ __align__(16) unsigned char smK[2 * 64 * 128];
    __shared__ __align__(16) unsigned char smVt[2 * 64 * 128];
    __shared__ __align__(16) unsigned char smP[4 * 16 * 128];
    __shared__ float qrel_s[64][4];
    __shared__ float relv_s[NREL][64];

    const unsigned short* qsrc  = qb + ((size_t)(b * S_LEN + s0)) * EMB + h * DPH;
    const unsigned short* ksrc  = kb + ((size_t)b * S_LEN) * EMB + h * DPH;
    const unsigned short* vsrcT = vbT + (size_t)(b * NHEAD + h) * DPH * S_LEN;

    // --- stage Q (64x64 bf16, swizzled) + rel_v ---
    #pragma unroll
    for (int it = 0; it < 2; ++it) {
        int w = it * 256 + tid;
        int row = w >> 3, kc = w & 7;
        uint4 raw = *reinterpret_cast<const uint4*>(qsrc + (size_t)row * EMB + kc * 8);
        unsigned byte = ((unsigned)row << 7) + ((unsigned)kc << 4);
        byte ^= (unsigned)((row & 7) << 4);
        *reinterpret_cast<uint4*>(smQ + byte) = raw;
    }
    if (tid < NREL * 64) {
        int rr = tid >> 6, d = tid & 63;
        relv_s[rr][d] = rel_v[rr * DPH + d];
    }
    __syncthreads();
    if (tid < 192) {
        int r = tid / 3, rr = tid - 3 * (tid / 3);
        float s = 0.f;
        #pragma unroll
        for (int dc = 0; dc < 32; ++dc) {
            unsigned byte = ((unsigned)r << 7) + (unsigned)(dc << 2);
            byte ^= (unsigned)((r & 7) << 4);
            unsigned u = *reinterpret_cast<const unsigned*>(smQ + byte);
            s += bf2f((unsigned short)(u & 0xffff)) * rel_k[rr * DPH + dc * 2]
               + bf2f((unsigned short)(u >> 16))   * rel_k[rr * DPH + dc * 2 + 1];
        }
        qrel_s[r][rr] = s;
    }
    __syncthreads();

    const int srow = wid * 16 + sl;
    const float qr0 = qrel_s[srow][0], qr1 = qrel_s[srow][1], qr2 = qrel_s[srow][2];

    bf16x8 qfrag[2];
    #pragma unroll
    for (int ks = 0; ks < 2; ++ks) {
        unsigned byte = ((unsigned)srow << 7) + (unsigned)(ks << 6) + (unsigned)(tg << 4);
        byte ^= (unsigned)((srow & 7) << 4);
        qfrag[ks] = *reinterpret_cast<const bf16x8*>(smQ + byte);
    }

    const int* rrow_s = rel + ((size_t)(b * S_LEN + s0 + srow)) * S_LEN;
    const unsigned pbase = (unsigned)(wid * 2048);

    float m_run = -1e30f, l_run = 0.f;
    float es[NREL] = {};
    f32x4 acc_pv[4] = {};

    auto loadKV = [&](int t0, uint4 (&kr)[2], uint4 (&vr)[2]) {
        #pragma unroll
        for (int it = 0; it < 2; ++it) {
            int w = it * 256 + tid;
            int row = w >> 3, kc = w & 7;
            kr[it] = *reinterpret_cast<const uint4*>(ksrc + (size_t)(t0 + row) * EMB + kc * 8);
            vr[it] = *reinterpret_cast<const uint4*>(vsrcT + (size_t)row * S_LEN + t0 + kc * 8);
        }
    };
    auto loadRel = [&](int t0, int4 (&rr)[4]) {
        #pragma unroll
        for (int t4 = 0; t4 < 4; ++t4)
            rr[t4] = *reinterpret_cast<const int4*>(rrow_s + t0 + t4 * 16 + tg * 4);
    };
    auto writeKV = [&](int buf, const uint4 (&kr)[2], const uint4 (&vr)[2]) {
        #pragma unroll
        for (int it = 0; it < 2; ++it) {
            int w = it * 256 + tid;
            int row = w >> 3, kc = w & 7;
            unsigned byte = ((unsigned)row << 7) + ((unsigned)kc << 4);
            byte ^= (unsigned)((row & 7) << 4);
            *reinterpret_cast<uint4*>(smK + buf * 8192 + byte) = kr[it];
            *reinterpret_cast<uint4*>(smVt + buf * 8192 + byte) = vr[it];
        }
    };
    auto computeTile = [&](int buf, const int4 (&rr)[4]) {
        const unsigned char* smKb = smK + buf * 8192;
        const unsigned char* smVb = smVt + buf * 8192;
        const float scale = 0.125f;
        f32x4 sacc[4] = {};
        #pragma unroll
        for (int ks = 0; ks < 2; ++ks)
            #pragma unroll
            for (int t4 = 0; t4 < 4; ++t4) {
                int trow = t4 * 16 + sl;
                unsigned byte = ((unsigned)trow << 7) + (unsigned)(ks << 6) + (unsigned)(tg << 4);
                byte ^= (unsigned)((trow & 7) << 4);
                bf16x8 kf = *reinterpret_cast<const bf16x8*>(smKb + byte);
                sacc[t4] = __builtin_amdgcn_mfma_f32_16x16x32_bf16(kf, qfrag[ks], sacc[t4], 0, 0, 0);
            }

        int rvv[4][4];
        float mt = -1e30f;
        #pragma unroll
        for (int t4 = 0; t4 < 4; ++t4) {
            int rv[4] = {rr[t4].x, rr[t4].y, rr[t4].z, rr[t4].w};
            #pragma unroll
            for (int j = 0; j < 4; ++j) {
                int r = rv[j]; r = r < 0 ? 0 : (r > 2 ? 2 : r);
                rvv[t4][j] = r;
                float qa = (r == 0) ? qr0 : ((r == 1) ? qr1 : qr2);
                float v = (sacc[t4][j] + qa) * scale;
                sacc[t4][j] = v;
                mt = fmaxf(mt, v);
            }
        }
        mt = fmaxf(mt, __shfl_xor(mt, 16));
        mt = fmaxf(mt, __shfl_xor(mt, 32));

        float mn = fmaxf(m_run, mt);
        float al = __expf(m_run - mn);
        m_run = mn;

        float ps = 0.f;
        #pragma unroll
        for (int t4 = 0; t4 < 4; ++t4)
            #pragma unroll
            for (int j = 0; j < 4; ++j) {
                float p = __expf(sacc[t4][j] - mn);
                sacc[t4][j] = p;
                ps += p;
            }
        float pst = ps;
        pst += __shfl_xor(pst, 16);
        pst += __shfl_xor(pst, 32);
        l_run = l_run * al + pst;

        #pragma unroll
        for (int r2 = 0; r2 < NREL; ++r2) {
            float e2 = es[r2] * al;
            #pragma unroll
            for (int t4 = 0; t4 < 4; ++t4)
                #pragma unroll
                for (int j = 0; j < 4; ++j)
                    e2 += (rvv[t4][j] == r2) ? sacc[t4][j] : 0.f;
            es[r2] = e2;
        }

        float al_s[4];
        #pragma unroll
        for (int r = 0; r < 4; ++r) al_s[r] = __shfl(al, tg * 4 + r);
        #pragma unroll
        for (int dt = 0; dt < 4; ++dt)
            #pragma unroll
            for (int r = 0; r < 4; ++r) acc_pv[dt][r] *= al_s[r];

        #pragma unroll
        for (int t4 = 0; t4 < 4; ++t4)
            #pragma unroll
            for (int pr = 0; pr < 2; ++pr) {
                unsigned u = (unsigned)f2bf(sacc[t4][2 * pr]) |
                             ((unsigned)f2bf(sacc[t4][2 * pr + 1]) << 16);
                unsigned byte = pbase + ((unsigned)sl << 7) + (unsigned)(t4 * 32 + tg * 8 + pr * 4);
                byte ^= (unsigned)((sl & 7) << 4);
                *reinterpret_cast<unsigned*>(smP + byte) = u;
            }

        #pragma unroll
        for (int ks = 0; ks < 2; ++ks) {
            unsigned pbyte = pbase + ((unsigned)sl << 7) + (unsigned)(ks << 6) + (unsigned)(tg << 4);
            pbyte ^= (unsigned)((sl & 7) << 4);
            bf16x8 pf = *reinterpret_cast<const bf16x8*>(smP + pbyte);
            #pragma unroll
            for (int dt = 0; dt < 4; ++dt) {
                int d = dt * 16 + sl;
                unsigned vbyte = ((unsigned)d << 7) + (unsigned)(ks << 6) + (unsigned)(tg << 4);
                vbyte ^= (unsigned)((d & 7) << 4);
                bf16x8 vf = *reinterpret_cast<const bf16x8*>(smVb + vbyte);
                acc_pv[dt] = __builtin_amdgcn_mfma_f32_16x16x32_bf16(pf, vf, acc_pv[dt], 0, 0, 0);
            }
        }
    };

    uint4 kr0[2], vr0[2], kr1[2], vr1[2];
    int4  rr0[4], rr1[4];
    loadKV(0, kr0, vr0);
    loadRel(0, rr0);

    #pragma unroll
    for (int tt2 = 0; tt2 < 4; ++tt2) {
        const int te = tt2 * 2;
        // even tile -> buf 0, regs set 0; prefetch into set 1
        writeKV(0, kr0, vr0);
        __syncthreads();
        loadKV((te + 1) * 64, kr1, vr1);
        loadRel((te + 1) * 64, rr1);
        computeTile(0, rr0);

        // odd tile -> buf 1, regs set 1; prefetch into set 0
        writeKV(1, kr1, vr1);
        __syncthreads();
        if (te + 2 < 8) { loadKV((te + 2) * 64, kr0, vr0); loadRel((te + 2) * 64, rr0); }
        computeTile(1, rr1);
    }

    // es: per-lane partial over this lane's t-quarter -> cross-reduce
    #pragma unroll
    for (int r2 = 0; r2 < NREL; ++r2) {
        es[r2] += __shfl_xor(es[r2], 16);
        es[r2] += __shfl_xor(es[r2], 32);
    }

    float l_s[4], es_s[NREL][4];
    #pragma unroll
    for (int r = 0; r < 4; ++r) {
        l_s[r] = __shfl(l_run, tg * 4 + r);
        #pragma unroll
        for (int r2 = 0; r2 < NREL; ++r2) es_s[r2][r] = __shfl(es[r2], tg * 4 + r);
    }

    unsigned short* dst = ob + ((size_t)(b * S_LEN + s0 + wid * 16)) * EMB + h * DPH;
    #pragma unroll
    for (int dt = 0; dt < 4; ++dt) {
        int d = dt * 16 + sl;
        float rv0 = relv_s[0][d], rv1 = relv_s[1][d], rv2 = relv_s[2][d];
        #pragma unroll
        for (int r = 0; r < 4; ++r) {
            int srowo = tg * 4 + r;
            float o = acc_pv[dt][r] + es_s[0][r] * rv0 + es_s[1][r] * rv1 + es_s[2][r] * rv2;
            o /= l_s[r];
            dst[(size_t)srowo * EMB + d] = f2bf(o);
        }
    }
}

extern "C" void kernel_launch(void* const* d_in, const int* in_sizes, int n_in,
                              void* d_out, int out_size, void* d_ws, size_t ws_size,
                              hipStream_t stream) {
    int iq=0, ik=1, iv=2, irel=3, iWq=4, ibq=5, iWk=6, ibk=7, iWv=8, ibv=9, iWo=10, ibo=11, irk=12, irv=13;
    if (n_in >= 14 && in_sizes[0] == 512 * 512) {
        iWk=0; iWo=1; iWq=2; iWv=3; ibk=4; ibo=5; ibq=6; ibv=7;
        irel=8; ik=9; iq=10; irk=11; irv=12; iv=13;
    }

    const float* q_in = (const float*)d_in[iq];
    const float* k_in = (const float*)d_in[ik];
    const float* v_in = (const float*)d_in[iv];
    const int*   grel = (const int*)d_in[irel];
    const float* Wq = (const float*)d_in[iWq];
    const float* bq = (const float*)d_in[ibq];
    const float* Wk = (const float*)d_in[iWk];
    const float* bk = (const float*)d_in[ibk];
    const float* Wv = (const float*)d_in[iWv];
    const float* bv = (const float*)d_in[ibv];
    const float* Wo = (const float*)d_in[iWo];
    const float* bo = (const float*)d_in[ibo];
    const float* rk = (const float*)d_in[irk];
    const float* rv = (const float*)d_in[irv];

    unsigned short* qb  = (unsigned short*)d_ws;
    unsigned short* kb  = qb + (size_t)4096 * 512;
    unsigned short* vbT = kb + (size_t)4096 * 512;   // [b*NHEAD+h][d][s]
    unsigned short* ab  = vbT + (size_t)4096 * 512;
    unsigned short* wt  = ab + (size_t)4096 * 512;

    dim3 blk(256);
    transpose_w<<<dim3(8, 8, 4), blk, 0, stream>>>(Wq, Wk, Wv, Wo, wt);
    gemm_proj_mfma<<<dim3(8, 32, 3), blk, 0, stream>>>(q_in, k_in, v_in, wt, bq, bk, bv, qb, kb, vbT);
    attn_mfma<<<dim3(8, NHEAD, BATCH), blk, 0, stream>>>(qb, kb, vbT, grel, rk, rv, ab);
    gemm_out_mfma<<<dim3(8, 32), blk, 0, stream>>>(ab, wt + (size_t)3 * 512 * 512, bo, (float*)d_out);
}

// Round 9
// 93.326 us; speedup vs baseline: 1.9859x; 1.9859x over previous
//
#include <hip/hip_runtime.h>
#include <hip/hip_bf16.h>

#define S_LEN 512
#define EMB   512
#define NHEAD 8
#define DPH   64
#define NREL  3
#define BATCH 8

typedef __attribute__((ext_vector_type(8))) short bf16x8;
typedef __attribute__((ext_vector_type(4))) float f32x4;

__device__ __forceinline__ float bf2f(unsigned short u) {
    union { unsigned int i; float f; } cv;
    cv.i = ((unsigned int)u) << 16;
    return cv.f;
}
__device__ __forceinline__ unsigned short f2bf(float f) {
    __hip_bfloat16 h = __float2bfloat16(f);
    return *reinterpret_cast<unsigned short*>(&h);
}

// ---------------------------------------------------------------------------
// Weight transpose: Wt[z][n][k] (bf16) = W[z][k][n] (f32), z in {q,k,v,o}.
// ---------------------------------------------------------------------------
__global__ __launch_bounds__(256) void transpose_w(
    const float* __restrict__ Wq, const float* __restrict__ Wk,
    const float* __restrict__ Wv, const float* __restrict__ Wo,
    unsigned short* __restrict__ Wt)
{
    const int z = blockIdx.z;
    const float* W = (z == 0) ? Wq : (z == 1) ? Wk : (z == 2) ? Wv : Wo;
    unsigned short* dst = Wt + (size_t)z * EMB * EMB;

    __shared__ float tile[64][65];
    const int n0 = blockIdx.x * 64, k0 = blockIdx.y * 64;
    const int t = threadIdx.x;
    const int cr = t >> 4, cc = (t & 15) * 4;

    #pragma unroll
    for (int it = 0; it < 4; ++it) {
        int r = cr + it * 16;
        float4 v = *reinterpret_cast<const float4*>(W + (size_t)(k0 + r) * EMB + n0 + cc);
        tile[r][cc + 0] = v.x; tile[r][cc + 1] = v.y;
        tile[r][cc + 2] = v.z; tile[r][cc + 3] = v.w;
    }
    __syncthreads();
    #pragma unroll
    for (int it = 0; it < 4; ++it) {
        int n = cr + it * 16;
        ushort4 o;
        o.x = f2bf(tile[cc + 0][n]); o.y = f2bf(tile[cc + 1][n]);
        o.z = f2bf(tile[cc + 2][n]); o.w = f2bf(tile[cc + 3][n]);
        *reinterpret_cast<ushort4*>(dst + (size_t)(n0 + n) * EMB + k0 + cc) = o;
    }
}

// ---------------------------------------------------------------------------
// MFMA projection GEMM. 128x64 tile, 4 waves 2x2.
// z==2 (V) writes TRANSPOSED per-head: vbT[(b*NHEAD+h)*DPH + d][s] (bf16).
// ---------------------------------------------------------------------------
__global__ __launch_bounds__(256) void gemm_proj_mfma(
    const float* __restrict__ Aq, const float* __restrict__ Ak, const float* __restrict__ Av,
    const unsigned short* __restrict__ Wt,
    const float* __restrict__ bqp, const float* __restrict__ bkp, const float* __restrict__ bvp,
    unsigned short* __restrict__ oq, unsigned short* __restrict__ okp, unsigned short* __restrict__ ov)
{
    const int z = blockIdx.z;
    const float* A = (z == 0) ? Aq : (z == 1) ? Ak : Av;
    const unsigned short* W = Wt + (size_t)z * EMB * EMB;
    const float* bias = (z == 0) ? bqp : (z == 1) ? bkp : bvp;
    unsigned short* out = (z == 0) ? oq : (z == 1) ? okp : ov;

    const int n0 = blockIdx.x * 64;
    const int m0 = blockIdx.y * 128;
    const int tid = threadIdx.x;
    const int lane = tid & 63;
    const int wid = tid >> 6;
    const int wr = wid >> 1, wc = wid & 1;

    __shared__ __align__(16) unsigned char smA[128 * 64 * 2];
    __shared__ __align__(16) unsigned char smB[64 * 64 * 2];

    f32x4 acc[4][2] = {};

    for (int k0 = 0; k0 < EMB; k0 += 64) {
        __syncthreads();
        #pragma unroll
        for (int it = 0; it < 4; ++it) {
            int w = it * 256 + tid;
            int row = w >> 3, kc = w & 7;
            const float* src = A + (size_t)(m0 + row) * EMB + k0 + kc * 8;
            float4 v0 = *reinterpret_cast<const float4*>(src);
            float4 v1 = *reinterpret_cast<const float4*>(src + 4);
            union { unsigned short s[8]; uint4 u; } p;
            p.s[0] = f2bf(v0.x); p.s[1] = f2bf(v0.y); p.s[2] = f2bf(v0.z); p.s[3] = f2bf(v0.w);
            p.s[4] = f2bf(v1.x); p.s[5] = f2bf(v1.y); p.s[6] = f2bf(v1.z); p.s[7] = f2bf(v1.w);
            unsigned byte = ((unsigned)row << 7) + ((unsigned)kc << 4);
            byte ^= (unsigned)((row & 7) << 4);
            *reinterpret_cast<uint4*>(smA + byte) = p.u;
        }
        #pragma unroll
        for (int it = 0; it < 2; ++it) {
            int w = it * 256 + tid;
            int row = w >> 3, kc = w & 7;
            uint4 raw = *reinterpret_cast<const uint4*>(W + (size_t)(n0 + row) * EMB + k0 + kc * 8);
            unsigned byte = ((unsigned)row << 7) + ((unsigned)kc << 4);
            byte ^= (unsigned)((row & 7) << 4);
            *reinterpret_cast<uint4*>(smB + byte) = raw;
        }
        __syncthreads();

        #pragma unroll
        for (int ks = 0; ks < 2; ++ks) {
            bf16x8 bfrag[2];
            #pragma unroll
            for (int ni = 0; ni < 2; ++ni) {
                int col = wc * 32 + ni * 16 + (lane & 15);
                unsigned byte = ((unsigned)col << 7) + (unsigned)(ks << 6) + (unsigned)((lane >> 4) << 4);
                byte ^= (unsigned)((col & 7) << 4);
                bfrag[ni] = *reinterpret_cast<const bf16x8*>(smB + byte);
            }
            #pragma unroll
            for (int mi = 0; mi < 4; ++mi) {
                int row = wr * 64 + mi * 16 + (lane & 15);
                unsigned byte = ((unsigned)row << 7) + (unsigned)(ks << 6) + (unsigned)((lane >> 4) << 4);
                byte ^= (unsigned)((row & 7) << 4);
                bf16x8 afrag = *reinterpret_cast<const bf16x8*>(smA + byte);
                #pragma unroll
                for (int ni = 0; ni < 2; ++ni)
                    acc[mi][ni] = __builtin_amdgcn_mfma_f32_16x16x32_bf16(afrag, bfrag[ni], acc[mi][ni], 0, 0, 0);
            }
        }
    }

    if (z == 2) {
        #pragma unroll
        for (int ni = 0; ni < 2; ++ni) {
            int colg = n0 + wc * 32 + ni * 16 + (lane & 15);
            float bj = bias[colg];
            int hh = colg >> 6, dd = colg & 63;
            #pragma unroll
            for (int mi = 0; mi < 4; ++mi) {
                int rbase = m0 + wr * 64 + mi * 16 + ((lane >> 4) << 2);
                int bb = rbase >> 9, ss = rbase & 511;
                ushort4 o;
                o.x = f2bf(acc[mi][ni][0] + bj);
                o.y = f2bf(acc[mi][ni][1] + bj);
                o.z = f2bf(acc[mi][ni][2] + bj);
                o.w = f2bf(acc[mi][ni][3] + bj);
                *reinterpret_cast<ushort4*>(out + ((size_t)(bb * NHEAD + hh) * DPH + dd) * S_LEN + ss) = o;
            }
        }
    } else {
        #pragma unroll
        for (int ni = 0; ni < 2; ++ni) {
            int colg = n0 + wc * 32 + ni * 16 + (lane & 15);
            float bj = bias[colg];
            #pragma unroll
            for (int mi = 0; mi < 4; ++mi) {
                int rbase = m0 + wr * 64 + mi * 16 + ((lane >> 4) << 2);
                #pragma unroll
                for (int q = 0; q < 4; ++q)
                    out[(size_t)(rbase + q) * EMB + colg] = f2bf(acc[mi][ni][q] + bj);
            }
        }
    }
}

// ---------------------------------------------------------------------------
// MFMA output GEMM (validated round 5).
// ---------------------------------------------------------------------------
__global__ __launch_bounds__(256) void gemm_out_mfma(
    const unsigned short* __restrict__ A,
    const unsigned short* __restrict__ W,
    const float* __restrict__ bias,
    float* __restrict__ out)
{
    const int n0 = blockIdx.x * 64;
    const int m0 = blockIdx.y * 128;
    const int tid = threadIdx.x;
    const int lane = tid & 63;
    const int wid = tid >> 6;
    const int wr = wid >> 1, wc = wid & 1;

    __shared__ __align__(16) unsigned char smA[128 * 64 * 2];
    __shared__ __align__(16) unsigned char smB[64 * 64 * 2];

    f32x4 acc[4][2] = {};

    for (int k0 = 0; k0 < EMB; k0 += 64) {
        __syncthreads();
        #pragma unroll
        for (int it = 0; it < 4; ++it) {
            int w = it * 256 + tid;
            int row = w >> 3, kc = w & 7;
            uint4 raw = *reinterpret_cast<const uint4*>(A + (size_t)(m0 + row) * EMB + k0 + kc * 8);
            unsigned byte = ((unsigned)row << 7) + ((unsigned)kc << 4);
            byte ^= (unsigned)((row & 7) << 4);
            *reinterpret_cast<uint4*>(smA + byte) = raw;
        }
        #pragma unroll
        for (int it = 0; it < 2; ++it) {
            int w = it * 256 + tid;
            int row = w >> 3, kc = w & 7;
            uint4 raw = *reinterpret_cast<const uint4*>(W + (size_t)(n0 + row) * EMB + k0 + kc * 8);
            unsigned byte = ((unsigned)row << 7) + ((unsigned)kc << 4);
            byte ^= (unsigned)((row & 7) << 4);
            *reinterpret_cast<uint4*>(smB + byte) = raw;
        }
        __syncthreads();

        #pragma unroll
        for (int ks = 0; ks < 2; ++ks) {
            bf16x8 bfrag[2];
            #pragma unroll
            for (int ni = 0; ni < 2; ++ni) {
                int col = wc * 32 + ni * 16 + (lane & 15);
                unsigned byte = ((unsigned)col << 7) + (unsigned)(ks << 6) + (unsigned)((lane >> 4) << 4);
                byte ^= (unsigned)((col & 7) << 4);
                bfrag[ni] = *reinterpret_cast<const bf16x8*>(smB + byte);
            }
            #pragma unroll
            for (int mi = 0; mi < 4; ++mi) {
                int row = wr * 64 + mi * 16 + (lane & 15);
                unsigned byte = ((unsigned)row << 7) + (unsigned)(ks << 6) + (unsigned)((lane >> 4) << 4);
                byte ^= (unsigned)((row & 7) << 4);
                bf16x8 afrag = *reinterpret_cast<const bf16x8*>(smA + byte);
                #pragma unroll
                for (int ni = 0; ni < 2; ++ni)
                    acc[mi][ni] = __builtin_amdgcn_mfma_f32_16x16x32_bf16(afrag, bfrag[ni], acc[mi][ni], 0, 0, 0);
            }
        }
    }

    #pragma unroll
    for (int ni = 0; ni < 2; ++ni) {
        int colg = n0 + wc * 32 + ni * 16 + (lane & 15);
        float bj = bias[colg];
        #pragma unroll
        for (int mi = 0; mi < 4; ++mi) {
            int rbase = m0 + wr * 64 + mi * 16 + ((lane >> 4) << 2);
            #pragma unroll
            for (int q = 0; q < 4; ++q)
                out[(size_t)(rbase + q) * EMB + colg] = acc[mi][ni][q] + bj;
        }
    }
}

// ---------------------------------------------------------------------------
// MFMA relation-aware flash attention, v3:
// Same schedule as v2 (dbuf LDS, one barrier/tile, reg prefetch, linear V^T)
// but NO lambdas — fully-unrolled loop, prefetch arrays indexed by tt&1
// (compile-time after unroll) so everything stays in VGPRs.
// ---------------------------------------------------------------------------
__global__ __launch_bounds__(256) void attn_mfma(
    const unsigned short* __restrict__ qb,
    const unsigned short* __restrict__ kb,
    const unsigned short* __restrict__ vbT,
    const int* __restrict__ rel,
    const float* __restrict__ rel_k, const float* __restrict__ rel_v,
    unsigned short* __restrict__ ob)
{
    const int s0 = blockIdx.x * 64;
    const int h  = blockIdx.y;
    const int b  = blockIdx.z;
    const int tid = threadIdx.x;
    const int lane = tid & 63;
    const int wid = tid >> 6;
    const int sl = lane & 15;
    const int tg = lane >> 4;

    __shared__ __align__(16) unsigned char smQ[64 * 128];
    __shared__ __align__(16) unsigned char smK[2 * 64 * 128];
    __shared__ __align__(16) unsigned char smVt[2 * 64 * 128];
    __shared__ __align__(16) unsigned char smP[4 * 16 * 128];
    __shared__ float qrel_s[64][4];
    __shared__ float relv_s[NREL][64];

    const unsigned short* qsrc  = qb + ((size_t)(b * S_LEN + s0)) * EMB + h * DPH;
    const unsigned short* ksrc  = kb + ((size_t)b * S_LEN) * EMB + h * DPH;
    const unsigned short* vsrcT = vbT + (size_t)(b * NHEAD + h) * DPH * S_LEN;

    // --- stage Q (64x64 bf16, swizzled) + rel_v ---
    #pragma unroll
    for (int it = 0; it < 2; ++it) {
        int w = it * 256 + tid;
        int row = w >> 3, kc = w & 7;
        uint4 raw = *reinterpret_cast<const uint4*>(qsrc + (size_t)row * EMB + kc * 8);
        unsigned byte = ((unsigned)row << 7) + ((unsigned)kc << 4);
        byte ^= (unsigned)((row & 7) << 4);
        *reinterpret_cast<uint4*>(smQ + byte) = raw;
    }
    if (tid < NREL * 64) {
        int rr = tid >> 6, d = tid & 63;
        relv_s[rr][d] = rel_v[rr * DPH + d];
    }
    __syncthreads();
    if (tid < 192) {
        int r = tid / 3, rr = tid - 3 * (tid / 3);
        float s = 0.f;
        #pragma unroll
        for (int dc = 0; dc < 32; ++dc) {
            unsigned byte = ((unsigned)r << 7) + (unsigned)(dc << 2);
            byte ^= (unsigned)((r & 7) << 4);
            unsigned u = *reinterpret_cast<const unsigned*>(smQ + byte);
            s += bf2f((unsigned short)(u & 0xffff)) * rel_k[rr * DPH + dc * 2]
               + bf2f((unsigned short)(u >> 16))   * rel_k[rr * DPH + dc * 2 + 1];
        }
        qrel_s[r][rr] = s;
    }
    __syncthreads();

    const int srow = wid * 16 + sl;
    const float qr0 = qrel_s[srow][0], qr1 = qrel_s[srow][1], qr2 = qrel_s[srow][2];

    bf16x8 qfrag[2];
    #pragma unroll
    for (int ks = 0; ks < 2; ++ks) {
        unsigned byte = ((unsigned)srow << 7) + (unsigned)(ks << 6) + (unsigned)(tg << 4);
        byte ^= (unsigned)((srow & 7) << 4);
        qfrag[ks] = *reinterpret_cast<const bf16x8*>(smQ + byte);
    }

    const int* rrow_s = rel + ((size_t)(b * S_LEN + s0 + srow)) * S_LEN;
    const unsigned pbase = (unsigned)(wid * 2048);
    const float scale = 0.125f;

    const int ldrow = tid >> 3;       // 0..31
    const int ldkc  = tid & 7;        // 0..7
    const unsigned wbyte0 = (((unsigned)ldrow << 7) + ((unsigned)ldkc << 4))
                            ^ ((unsigned)((ldrow & 7) << 4));
    const unsigned wbyte1 = wbyte0 + 4096;   // row+32: same swizzle bits

    float m_run = -1e30f, l_run = 0.f;
    float es[NREL] = {};
    f32x4 acc_pv[4] = {};

    uint4 kpre[2][2], vpre[2][2];
    int4  rpre[2][4];

    // prefetch tile 0 -> set 0
    kpre[0][0] = *reinterpret_cast<const uint4*>(ksrc + (size_t)ldrow * EMB + ldkc * 8);
    kpre[0][1] = *reinterpret_cast<const uint4*>(ksrc + (size_t)(ldrow + 32) * EMB + ldkc * 8);
    vpre[0][0] = *reinterpret_cast<const uint4*>(vsrcT + (size_t)ldrow * S_LEN + ldkc * 8);
    vpre[0][1] = *reinterpret_cast<const uint4*>(vsrcT + (size_t)(ldrow + 32) * S_LEN + ldkc * 8);
    #pragma unroll
    for (int t4 = 0; t4 < 4; ++t4)
        rpre[0][t4] = *reinterpret_cast<const int4*>(rrow_s + t4 * 16 + tg * 4);

    #pragma unroll
    for (int tt = 0; tt < 8; ++tt) {
        const int cur = tt & 1, nxt = cur ^ 1;

        // write current prefetched tile into LDS buf `cur`
        *reinterpret_cast<uint4*>(smK  + cur * 8192 + wbyte0) = kpre[cur][0];
        *reinterpret_cast<uint4*>(smK  + cur * 8192 + wbyte1) = kpre[cur][1];
        *reinterpret_cast<uint4*>(smVt + cur * 8192 + wbyte0) = vpre[cur][0];
        *reinterpret_cast<uint4*>(smVt + cur * 8192 + wbyte1) = vpre[cur][1];
        __syncthreads();

        // issue next tile's loads (overlap with compute below)
        if (tt + 1 < 8) {
            const int t0n = (tt + 1) * 64;
            kpre[nxt][0] = *reinterpret_cast<const uint4*>(ksrc + (size_t)(t0n + ldrow) * EMB + ldkc * 8);
            kpre[nxt][1] = *reinterpret_cast<const uint4*>(ksrc + (size_t)(t0n + ldrow + 32) * EMB + ldkc * 8);
            vpre[nxt][0] = *reinterpret_cast<const uint4*>(vsrcT + (size_t)ldrow * S_LEN + t0n + ldkc * 8);
            vpre[nxt][1] = *reinterpret_cast<const uint4*>(vsrcT + (size_t)(ldrow + 32) * S_LEN + t0n + ldkc * 8);
            #pragma unroll
            for (int t4 = 0; t4 < 4; ++t4)
                rpre[nxt][t4] = *reinterpret_cast<const int4*>(rrow_s + t0n + t4 * 16 + tg * 4);
        }

        // ---- compute tile tt from buf `cur` ----
        const unsigned char* smKb = smK + cur * 8192;
        const unsigned char* smVb = smVt + cur * 8192;

        f32x4 sacc[4] = {};
        #pragma unroll
        for (int ks = 0; ks < 2; ++ks)
            #pragma unroll
            for (int t4 = 0; t4 < 4; ++t4) {
                int trow = t4 * 16 + sl;
                unsigned byte = ((unsigned)trow << 7) + (unsigned)(ks << 6) + (unsigned)(tg << 4);
                byte ^= (unsigned)((trow & 7) << 4);
                bf16x8 kf = *reinterpret_cast<const bf16x8*>(smKb + byte);
                sacc[t4] = __builtin_amdgcn_mfma_f32_16x16x32_bf16(kf, qfrag[ks], sacc[t4], 0, 0, 0);
            }

        int rvv[4][4];
        float mt = -1e30f;
        #pragma unroll
        for (int t4 = 0; t4 < 4; ++t4) {
            int rv[4] = {rpre[cur][t4].x, rpre[cur][t4].y, rpre[cur][t4].z, rpre[cur][t4].w};
            #pragma unroll
            for (int j = 0; j < 4; ++j) {
                int r = rv[j]; r = r < 0 ? 0 : (r > 2 ? 2 : r);
                rvv[t4][j] = r;
                float qa = (r == 0) ? qr0 : ((r == 1) ? qr1 : qr2);
                float v = (sacc[t4][j] + qa) * scale;
                sacc[t4][j] = v;
                mt = fmaxf(mt, v);
            }
        }
        mt = fmaxf(mt, __shfl_xor(mt, 16));
        mt = fmaxf(mt, __shfl_xor(mt, 32));

        float mn = fmaxf(m_run, mt);
        float al = __expf(m_run - mn);
        m_run = mn;

        float ps = 0.f;
        #pragma unroll
        for (int t4 = 0; t4 < 4; ++t4)
            #pragma unroll
            for (int j = 0; j < 4; ++j) {
                float p = __expf(sacc[t4][j] - mn);
                sacc[t4][j] = p;
                ps += p;
            }
        float pst = ps;
        pst += __shfl_xor(pst, 16);
        pst += __shfl_xor(pst, 32);
        l_run = l_run * al + pst;

        #pragma unroll
        for (int r2 = 0; r2 < NREL; ++r2) {
            float e2 = es[r2] * al;
            #pragma unroll
            for (int t4 = 0; t4 < 4; ++t4)
                #pragma unroll
                for (int j = 0; j < 4; ++j)
                    e2 += (rvv[t4][j] == r2) ? sacc[t4][j] : 0.f;
            es[r2] = e2;
        }

        float al_s[4];
        #pragma unroll
        for (int r = 0; r < 4; ++r) al_s[r] = __shfl(al, tg * 4 + r);
        #pragma unroll
        for (int dt = 0; dt < 4; ++dt)
            #pragma unroll
            for (int r = 0; r < 4; ++r) acc_pv[dt][r] *= al_s[r];

        // P -> LDS bf16 (per-wave region; same-wave write->read)
        #pragma unroll
        for (int t4 = 0; t4 < 4; ++t4)
            #pragma unroll
            for (int pr = 0; pr < 2; ++pr) {
                unsigned u = (unsigned)f2bf(sacc[t4][2 * pr]) |
                             ((unsigned)f2bf(sacc[t4][2 * pr + 1]) << 16);
                unsigned byte = pbase + ((unsigned)sl << 7) + (unsigned)(t4 * 32 + tg * 8 + pr * 4);
                byte ^= (unsigned)((sl & 7) << 4);
                *reinterpret_cast<unsigned*>(smP + byte) = u;
            }

        // PV: acc[s][d] += P[s][t] V[t][d]
        #pragma unroll
        for (int ks = 0; ks < 2; ++ks) {
            unsigned pbyte = pbase + ((unsigned)sl << 7) + (unsigned)(ks << 6) + (unsigned)(tg << 4);
            pbyte ^= (unsigned)((sl & 7) << 4);
            bf16x8 pf = *reinterpret_cast<const bf16x8*>(smP + pbyte);
            #pragma unroll
            for (int dt = 0; dt < 4; ++dt) {
                int d = dt * 16 + sl;
                unsigned vbyte = ((unsigned)d << 7) + (unsigned)(ks << 6) + (unsigned)(tg << 4);
                vbyte ^= (unsigned)((d & 7) << 4);
                bf16x8 vf = *reinterpret_cast<const bf16x8*>(smVb + vbyte);
                acc_pv[dt] = __builtin_amdgcn_mfma_f32_16x16x32_bf16(pf, vf, acc_pv[dt], 0, 0, 0);
            }
        }
    }

    // es: per-lane partial over this lane's t-quarter -> cross-reduce
    #pragma unroll
    for (int r2 = 0; r2 < NREL; ++r2) {
        es[r2] += __shfl_xor(es[r2], 16);
        es[r2] += __shfl_xor(es[r2], 32);
    }

    float l_s[4], es_s[NREL][4];
    #pragma unroll
    for (int r = 0; r < 4; ++r) {
        l_s[r] = __shfl(l_run, tg * 4 + r);
        #pragma unroll
        for (int r2 = 0; r2 < NREL; ++r2) es_s[r2][r] = __shfl(es[r2], tg * 4 + r);
    }

    unsigned short* dst = ob + ((size_t)(b * S_LEN + s0 + wid * 16)) * EMB + h * DPH;
    #pragma unroll
    for (int dt = 0; dt < 4; ++dt) {
        int d = dt * 16 + sl;
        float rv0 = relv_s[0][d], rv1 = relv_s[1][d], rv2 = relv_s[2][d];
        #pragma unroll
        for (int r = 0; r < 4; ++r) {
            int srowo = tg * 4 + r;
            float o = acc_pv[dt][r] + es_s[0][r] * rv0 + es_s[1][r] * rv1 + es_s[2][r] * rv2;
            o /= l_s[r];
            dst[(size_t)srowo * EMB + d] = f2bf(o);
        }
    }
}

extern "C" void kernel_launch(void* const* d_in, const int* in_sizes, int n_in,
                              void* d_out, int out_size, void* d_ws, size_t ws_size,
                              hipStream_t stream) {
    int iq=0, ik=1, iv=2, irel=3, iWq=4, ibq=5, iWk=6, ibk=7, iWv=8, ibv=9, iWo=10, ibo=11, irk=12, irv=13;
    if (n_in >= 14 && in_sizes[0] == 512 * 512) {
        iWk=0; iWo=1; iWq=2; iWv=3; ibk=4; ibo=5; ibq=6; ibv=7;
        irel=8; ik=9; iq=10; irk=11; irv=12; iv=13;
    }

    const float* q_in = (const float*)d_in[iq];
    const float* k_in = (const float*)d_in[ik];
    const float* v_in = (const float*)d_in[iv];
    const int*   grel = (const int*)d_in[irel];
    const float* Wq = (const float*)d_in[iWq];
    const float* bq = (const float*)d_in[ibq];
    const float* Wk = (const float*)d_in[iWk];
    const float* bk = (const float*)d_in[ibk];
    const float* Wv = (const float*)d_in[iWv];
    const float* bv = (const float*)d_in[ibv];
    const float* Wo = (const float*)d_in[iWo];
    const float* bo = (const float*)d_in[ibo];
    const float* rk = (const float*)d_in[irk];
    const float* rv = (const float*)d_in[irv];

    unsigned short* qb  = (unsigned short*)d_ws;
    unsigned short* kb  = qb + (size_t)4096 * 512;
    unsigned short* vbT = kb + (size_t)4096 * 512;   // [b*NHEAD+h][d][s]
    unsigned short* ab  = vbT + (size_t)4096 * 512;
    unsigned short* wt  = ab + (size_t)4096 * 512;

    dim3 blk(256);
    transpose_w<<<dim3(8, 8, 4), blk, 0, stream>>>(Wq, Wk, Wv, Wo, wt);
    gemm_proj_mfma<<<dim3(8, 32, 3), blk, 0, stream>>>(q_in, k_in, v_in, wt, bq, bk, bv, qb, kb, vbT);
    attn_mfma<<<dim3(8, NHEAD, BATCH), blk, 0, stream>>>(qb, kb, vbT, grel, rk, rv, ab);
    gemm_out_mfma<<<dim3(8, 32), blk, 0, stream>>>(ab, wt + (size_t)3 * 512 * 512, bo, (float*)d_out);
}

// Round 10
// 74.342 us; speedup vs baseline: 2.4930x; 1.2553x over previous
//
#include <hip/hip_runtime.h>
#include <hip/hip_bf16.h>

#define S_LEN 512
#define EMB   512
#define NHEAD 8
#define DPH   64
#define NREL  3
#define BATCH 8

typedef __attribute__((ext_vector_type(8))) short bf16x8;
typedef __attribute__((ext_vector_type(4))) float f32x4;

__device__ __forceinline__ float bf2f(unsigned short u) {
    union { unsigned int i; float f; } cv;
    cv.i = ((unsigned int)u) << 16;
    return cv.f;
}
__device__ __forceinline__ unsigned short f2bf(float f) {
    __hip_bfloat16 h = __float2bfloat16(f);
    return *reinterpret_cast<unsigned short*>(&h);
}

// ---------------------------------------------------------------------------
// Weight transpose: Wt[z][n][k] (bf16) = W[z][k][n] (f32), z in {q,k,v,o}.
// ---------------------------------------------------------------------------
__global__ __launch_bounds__(256) void transpose_w(
    const float* __restrict__ Wq, const float* __restrict__ Wk,
    const float* __restrict__ Wv, const float* __restrict__ Wo,
    unsigned short* __restrict__ Wt)
{
    const int z = blockIdx.z;
    const float* W = (z == 0) ? Wq : (z == 1) ? Wk : (z == 2) ? Wv : Wo;
    unsigned short* dst = Wt + (size_t)z * EMB * EMB;

    __shared__ float tile[64][65];
    const int n0 = blockIdx.x * 64, k0 = blockIdx.y * 64;
    const int t = threadIdx.x;
    const int cr = t >> 4, cc = (t & 15) * 4;

    #pragma unroll
    for (int it = 0; it < 4; ++it) {
        int r = cr + it * 16;
        float4 v = *reinterpret_cast<const float4*>(W + (size_t)(k0 + r) * EMB + n0 + cc);
        tile[r][cc + 0] = v.x; tile[r][cc + 1] = v.y;
        tile[r][cc + 2] = v.z; tile[r][cc + 3] = v.w;
    }
    __syncthreads();
    #pragma unroll
    for (int it = 0; it < 4; ++it) {
        int n = cr + it * 16;
        ushort4 o;
        o.x = f2bf(tile[cc + 0][n]); o.y = f2bf(tile[cc + 1][n]);
        o.z = f2bf(tile[cc + 2][n]); o.w = f2bf(tile[cc + 3][n]);
        *reinterpret_cast<ushort4*>(dst + (size_t)(n0 + n) * EMB + k0 + cc) = o;
    }
}

// ---------------------------------------------------------------------------
// MFMA projection GEMM. 128x64 tile, 4 waves 2x2.
// z==2 (V) writes TRANSPOSED per-head: vbT[(b*NHEAD+h)*DPH + d][s] (bf16).
// ---------------------------------------------------------------------------
__global__ __launch_bounds__(256) void gemm_proj_mfma(
    const float* __restrict__ Aq, const float* __restrict__ Ak, const float* __restrict__ Av,
    const unsigned short* __restrict__ Wt,
    const float* __restrict__ bqp, const float* __restrict__ bkp, const float* __restrict__ bvp,
    unsigned short* __restrict__ oq, unsigned short* __restrict__ okp, unsigned short* __restrict__ ov)
{
    const int z = blockIdx.z;
    const float* A = (z == 0) ? Aq : (z == 1) ? Ak : Av;
    const unsigned short* W = Wt + (size_t)z * EMB * EMB;
    const float* bias = (z == 0) ? bqp : (z == 1) ? bkp : bvp;
    unsigned short* out = (z == 0) ? oq : (z == 1) ? okp : ov;

    const int n0 = blockIdx.x * 64;
    const int m0 = blockIdx.y * 128;
    const int tid = threadIdx.x;
    const int lane = tid & 63;
    const int wid = tid >> 6;
    const int wr = wid >> 1, wc = wid & 1;

    __shared__ __align__(16) unsigned char smA[128 * 64 * 2];
    __shared__ __align__(16) unsigned char smB[64 * 64 * 2];

    f32x4 acc[4][2] = {};

    for (int k0 = 0; k0 < EMB; k0 += 64) {
        __syncthreads();
        #pragma unroll
        for (int it = 0; it < 4; ++it) {
            int w = it * 256 + tid;
            int row = w >> 3, kc = w & 7;
            const float* src = A + (size_t)(m0 + row) * EMB + k0 + kc * 8;
            float4 v0 = *reinterpret_cast<const float4*>(src);
            float4 v1 = *reinterpret_cast<const float4*>(src + 4);
            union { unsigned short s[8]; uint4 u; } p;
            p.s[0] = f2bf(v0.x); p.s[1] = f2bf(v0.y); p.s[2] = f2bf(v0.z); p.s[3] = f2bf(v0.w);
            p.s[4] = f2bf(v1.x); p.s[5] = f2bf(v1.y); p.s[6] = f2bf(v1.z); p.s[7] = f2bf(v1.w);
            unsigned byte = ((unsigned)row << 7) + ((unsigned)kc << 4);
            byte ^= (unsigned)((row & 7) << 4);
            *reinterpret_cast<uint4*>(smA + byte) = p.u;
        }
        #pragma unroll
        for (int it = 0; it < 2; ++it) {
            int w = it * 256 + tid;
            int row = w >> 3, kc = w & 7;
            uint4 raw = *reinterpret_cast<const uint4*>(W + (size_t)(n0 + row) * EMB + k0 + kc * 8);
            unsigned byte = ((unsigned)row << 7) + ((unsigned)kc << 4);
            byte ^= (unsigned)((row & 7) << 4);
            *reinterpret_cast<uint4*>(smB + byte) = raw;
        }
        __syncthreads();

        #pragma unroll
        for (int ks = 0; ks < 2; ++ks) {
            bf16x8 bfrag[2];
            #pragma unroll
            for (int ni = 0; ni < 2; ++ni) {
                int col = wc * 32 + ni * 16 + (lane & 15);
                unsigned byte = ((unsigned)col << 7) + (unsigned)(ks << 6) + (unsigned)((lane >> 4) << 4);
                byte ^= (unsigned)((col & 7) << 4);
                bfrag[ni] = *reinterpret_cast<const bf16x8*>(smB + byte);
            }
            #pragma unroll
            for (int mi = 0; mi < 4; ++mi) {
                int row = wr * 64 + mi * 16 + (lane & 15);
                unsigned byte = ((unsigned)row << 7) + (unsigned)(ks << 6) + (unsigned)((lane >> 4) << 4);
                byte ^= (unsigned)((row & 7) << 4);
                bf16x8 afrag = *reinterpret_cast<const bf16x8*>(smA + byte);
                #pragma unroll
                for (int ni = 0; ni < 2; ++ni)
                    acc[mi][ni] = __builtin_amdgcn_mfma_f32_16x16x32_bf16(afrag, bfrag[ni], acc[mi][ni], 0, 0, 0);
            }
        }
    }

    if (z == 2) {
        #pragma unroll
        for (int ni = 0; ni < 2; ++ni) {
            int colg = n0 + wc * 32 + ni * 16 + (lane & 15);
            float bj = bias[colg];
            int hh = colg >> 6, dd = colg & 63;
            #pragma unroll
            for (int mi = 0; mi < 4; ++mi) {
                int rbase = m0 + wr * 64 + mi * 16 + ((lane >> 4) << 2);
                int bb = rbase >> 9, ss = rbase & 511;
                ushort4 o;
                o.x = f2bf(acc[mi][ni][0] + bj);
                o.y = f2bf(acc[mi][ni][1] + bj);
                o.z = f2bf(acc[mi][ni][2] + bj);
                o.w = f2bf(acc[mi][ni][3] + bj);
                *reinterpret_cast<ushort4*>(out + ((size_t)(bb * NHEAD + hh) * DPH + dd) * S_LEN + ss) = o;
            }
        }
    } else {
        #pragma unroll
        for (int ni = 0; ni < 2; ++ni) {
            int colg = n0 + wc * 32 + ni * 16 + (lane & 15);
            float bj = bias[colg];
            #pragma unroll
            for (int mi = 0; mi < 4; ++mi) {
                int rbase = m0 + wr * 64 + mi * 16 + ((lane >> 4) << 2);
                #pragma unroll
                for (int q = 0; q < 4; ++q)
                    out[(size_t)(rbase + q) * EMB + colg] = f2bf(acc[mi][ni][q] + bj);
            }
        }
    }
}

// ---------------------------------------------------------------------------
// MFMA output GEMM (validated round 5).
// ---------------------------------------------------------------------------
__global__ __launch_bounds__(256) void gemm_out_mfma(
    const unsigned short* __restrict__ A,
    const unsigned short* __restrict__ W,
    const float* __restrict__ bias,
    float* __restrict__ out)
{
    const int n0 = blockIdx.x * 64;
    const int m0 = blockIdx.y * 128;
    const int tid = threadIdx.x;
    const int lane = tid & 63;
    const int wid = tid >> 6;
    const int wr = wid >> 1, wc = wid & 1;

    __shared__ __align__(16) unsigned char smA[128 * 64 * 2];
    __shared__ __align__(16) unsigned char smB[64 * 64 * 2];

    f32x4 acc[4][2] = {};

    for (int k0 = 0; k0 < EMB; k0 += 64) {
        __syncthreads();
        #pragma unroll
        for (int it = 0; it < 4; ++it) {
            int w = it * 256 + tid;
            int row = w >> 3, kc = w & 7;
            uint4 raw = *reinterpret_cast<const uint4*>(A + (size_t)(m0 + row) * EMB + k0 + kc * 8);
            unsigned byte = ((unsigned)row << 7) + ((unsigned)kc << 4);
            byte ^= (unsigned)((row & 7) << 4);
            *reinterpret_cast<uint4*>(smA + byte) = raw;
        }
        #pragma unroll
        for (int it = 0; it < 2; ++it) {
            int w = it * 256 + tid;
            int row = w >> 3, kc = w & 7;
            uint4 raw = *reinterpret_cast<const uint4*>(W + (size_t)(n0 + row) * EMB + k0 + kc * 8);
            unsigned byte = ((unsigned)row << 7) + ((unsigned)kc << 4);
            byte ^= (unsigned)((row & 7) << 4);
            *reinterpret_cast<uint4*>(smB + byte) = raw;
        }
        __syncthreads();

        #pragma unroll
        for (int ks = 0; ks < 2; ++ks) {
            bf16x8 bfrag[2];
            #pragma unroll
            for (int ni = 0; ni < 2; ++ni) {
                int col = wc * 32 + ni * 16 + (lane & 15);
                unsigned byte = ((unsigned)col << 7) + (unsigned)(ks << 6) + (unsigned)((lane >> 4) << 4);
                byte ^= (unsigned)((col & 7) << 4);
                bfrag[ni] = *reinterpret_cast<const bf16x8*>(smB + byte);
            }
            #pragma unroll
            for (int mi = 0; mi < 4; ++mi) {
                int row = wr * 64 + mi * 16 + (lane & 15);
                unsigned byte = ((unsigned)row << 7) + (unsigned)(ks << 6) + (unsigned)((lane >> 4) << 4);
                byte ^= (unsigned)((row & 7) << 4);
                bf16x8 afrag = *reinterpret_cast<const bf16x8*>(smA + byte);
                #pragma unroll
                for (int ni = 0; ni < 2; ++ni)
                    acc[mi][ni] = __builtin_amdgcn_mfma_f32_16x16x32_bf16(afrag, bfrag[ni], acc[mi][ni], 0, 0, 0);
            }
        }
    }

    #pragma unroll
    for (int ni = 0; ni < 2; ++ni) {
        int colg = n0 + wc * 32 + ni * 16 + (lane & 15);
        float bj = bias[colg];
        #pragma unroll
        for (int mi = 0; mi < 4; ++mi) {
            int rbase = m0 + wr * 64 + mi * 16 + ((lane >> 4) << 2);
            #pragma unroll
            for (int q = 0; q < 4; ++q)
                out[(size_t)(rbase + q) * EMB + colg] = acc[mi][ni][q] + bj;
        }
    }
}

// ---------------------------------------------------------------------------
// MFMA relation-aware flash attention, v4: in-block t-split.
// Block = 512 thr = 8 waves. Wave w: q-strip (w&3, 16 rows), t-half (w>>2,
// 4 tiles of 64). Each t-group single-buffers its own K/V^T LDS tile; global
// loads issued before the loop-top barrier (latency hides under barrier).
// After the loop both groups publish (m,l,es)+acc to LDS; group 0 merges
// (flash combine) and writes output. 4 waves/SIMD vs v3's 2.
// ---------------------------------------------------------------------------
__global__ __launch_bounds__(512) void attn_mfma(
    const unsigned short* __restrict__ qb,
    const unsigned short* __restrict__ kb,
    const unsigned short* __restrict__ vbT,
    const int* __restrict__ rel,
    const float* __restrict__ rel_k, const float* __restrict__ rel_v,
    unsigned short* __restrict__ ob)
{
    const int s0 = blockIdx.x * 64;
    const int h  = blockIdx.y;
    const int b  = blockIdx.z;
    const int tid = threadIdx.x;
    const int lane = tid & 63;
    const int wid = tid >> 6;          // 0..7
    const int qstrip = wid & 3;        // 16-row strip
    const int tgroup = wid >> 2;       // t-half
    const int sl = lane & 15;
    const int tg = lane >> 4;

    __shared__ __align__(16) unsigned char smQ[64 * 128];
    __shared__ __align__(16) unsigned char smK[2 * 64 * 128];   // per t-group
    __shared__ __align__(16) unsigned char smVt[2 * 64 * 128];  // per t-group
    __shared__ __align__(16) unsigned char smP[8 * 16 * 128];   // per wave
    __shared__ float qrel_s[64][4];
    __shared__ float relv_s[NREL][64];

    const unsigned short* qsrc  = qb + ((size_t)(b * S_LEN + s0)) * EMB + h * DPH;
    const unsigned short* ksrc  = kb + ((size_t)b * S_LEN) * EMB + h * DPH;
    const unsigned short* vsrcT = vbT + (size_t)(b * NHEAD + h) * DPH * S_LEN;

    // --- stage Q (64x64 bf16, swizzled): 512 thr x 1 uint4 ---
    {
        int row = tid >> 3, kc = tid & 7;
        uint4 raw = *reinterpret_cast<const uint4*>(qsrc + (size_t)row * EMB + kc * 8);
        unsigned byte = ((unsigned)row << 7) + ((unsigned)kc << 4);
        byte ^= (unsigned)((row & 7) << 4);
        *reinterpret_cast<uint4*>(smQ + byte) = raw;
    }
    if (tid < NREL * 64) {
        int rr = tid >> 6, d = tid & 63;
        relv_s[rr][d] = rel_v[rr * DPH + d];
    }
    __syncthreads();
    if (tid < 192) {
        int r = tid / 3, rr = tid - 3 * (tid / 3);
        float s = 0.f;
        #pragma unroll
        for (int dc = 0; dc < 32; ++dc) {
            unsigned byte = ((unsigned)r << 7) + (unsigned)(dc << 2);
            byte ^= (unsigned)((r & 7) << 4);
            unsigned u = *reinterpret_cast<const unsigned*>(smQ + byte);
            s += bf2f((unsigned short)(u & 0xffff)) * rel_k[rr * DPH + dc * 2]
               + bf2f((unsigned short)(u >> 16))   * rel_k[rr * DPH + dc * 2 + 1];
        }
        qrel_s[r][rr] = s;
    }
    __syncthreads();

    const int srow = qstrip * 16 + sl;       // block-local q-row for this lane
    const float qr0 = qrel_s[srow][0], qr1 = qrel_s[srow][1], qr2 = qrel_s[srow][2];

    bf16x8 qfrag[2];
    #pragma unroll
    for (int ks = 0; ks < 2; ++ks) {
        unsigned byte = ((unsigned)srow << 7) + (unsigned)(ks << 6) + (unsigned)(tg << 4);
        byte ^= (unsigned)((srow & 7) << 4);
        qfrag[ks] = *reinterpret_cast<const bf16x8*>(smQ + byte);
    }

    const int* rrow_s = rel + ((size_t)(b * S_LEN + s0 + srow)) * S_LEN;
    const unsigned pbase = (unsigned)(wid * 2048);
    const float scale = 0.125f;

    const int gtid  = tid & 255;      // thread id within t-group (4 waves)
    const int ldrow = gtid >> 3;      // 0..31
    const int ldkc  = gtid & 7;       // 0..7
    const unsigned wbyte0 = (((unsigned)ldrow << 7) + ((unsigned)ldkc << 4))
                            ^ ((unsigned)((ldrow & 7) << 4));
    const unsigned wbyte1 = wbyte0 + 4096;   // row+32: same swizzle bits
    unsigned char* kbase = smK  + tgroup * 8192;
    unsigned char* vbase = smVt + tgroup * 8192;

    float m_run = -1e30f, l_run = 0.f;
    float es[NREL] = {};
    f32x4 acc_pv[4] = {};

    #pragma unroll
    for (int i = 0; i < 4; ++i) {
        const int t0 = (tgroup * 4 + i) * 64;

        // issue this tile's global loads BEFORE the barrier (latency overlap)
        uint4 k0 = *reinterpret_cast<const uint4*>(ksrc + (size_t)(t0 + ldrow) * EMB + ldkc * 8);
        uint4 k1 = *reinterpret_cast<const uint4*>(ksrc + (size_t)(t0 + ldrow + 32) * EMB + ldkc * 8);
        uint4 v0 = *reinterpret_cast<const uint4*>(vsrcT + (size_t)ldrow * S_LEN + t0 + ldkc * 8);
        uint4 v1 = *reinterpret_cast<const uint4*>(vsrcT + (size_t)(ldrow + 32) * S_LEN + t0 + ldkc * 8);
        int4 rr[4];
        #pragma unroll
        for (int t4 = 0; t4 < 4; ++t4)
            rr[t4] = *reinterpret_cast<const int4*>(rrow_s + t0 + t4 * 16 + tg * 4);

        __syncthreads();   // prior compute's LDS reads done
        *reinterpret_cast<uint4*>(kbase + wbyte0) = k0;
        *reinterpret_cast<uint4*>(kbase + wbyte1) = k1;
        *reinterpret_cast<uint4*>(vbase + wbyte0) = v0;
        *reinterpret_cast<uint4*>(vbase + wbyte1) = v1;
        __syncthreads();

        // ---- QK^T: C[t][s] ----
        f32x4 sacc[4] = {};
        #pragma unroll
        for (int ks = 0; ks < 2; ++ks)
            #pragma unroll
            for (int t4 = 0; t4 < 4; ++t4) {
                int trow = t4 * 16 + sl;
                unsigned byte = ((unsigned)trow << 7) + (unsigned)(ks << 6) + (unsigned)(tg << 4);
                byte ^= (unsigned)((trow & 7) << 4);
                bf16x8 kf = *reinterpret_cast<const bf16x8*>(kbase + byte);
                sacc[t4] = __builtin_amdgcn_mfma_f32_16x16x32_bf16(kf, qfrag[ks], sacc[t4], 0, 0, 0);
            }

        int rvv[4][4];
        float mt = -1e30f;
        #pragma unroll
        for (int t4 = 0; t4 < 4; ++t4) {
            int rv[4] = {rr[t4].x, rr[t4].y, rr[t4].z, rr[t4].w};
            #pragma unroll
            for (int j = 0; j < 4; ++j) {
                int r = rv[j]; r = r < 0 ? 0 : (r > 2 ? 2 : r);
                rvv[t4][j] = r;
                float qa = (r == 0) ? qr0 : ((r == 1) ? qr1 : qr2);
                float v = (sacc[t4][j] + qa) * scale;
                sacc[t4][j] = v;
                mt = fmaxf(mt, v);
            }
        }
        mt = fmaxf(mt, __shfl_xor(mt, 16));
        mt = fmaxf(mt, __shfl_xor(mt, 32));

        float mn = fmaxf(m_run, mt);
        float al = __expf(m_run - mn);
        m_run = mn;

        float ps = 0.f;
        #pragma unroll
        for (int t4 = 0; t4 < 4; ++t4)
            #pragma unroll
            for (int j = 0; j < 4; ++j) {
                float p = __expf(sacc[t4][j] - mn);
                sacc[t4][j] = p;
                ps += p;
            }
        float pst = ps;
        pst += __shfl_xor(pst, 16);
        pst += __shfl_xor(pst, 32);
        l_run = l_run * al + pst;

        #pragma unroll
        for (int r2 = 0; r2 < NREL; ++r2) {
            float e2 = es[r2] * al;
            #pragma unroll
            for (int t4 = 0; t4 < 4; ++t4)
                #pragma unroll
                for (int j = 0; j < 4; ++j)
                    e2 += (rvv[t4][j] == r2) ? sacc[t4][j] : 0.f;
            es[r2] = e2;
        }

        float al_s[4];
        #pragma unroll
        for (int r = 0; r < 4; ++r) al_s[r] = __shfl(al, tg * 4 + r);
        #pragma unroll
        for (int dt = 0; dt < 4; ++dt)
            #pragma unroll
            for (int r = 0; r < 4; ++r) acc_pv[dt][r] *= al_s[r];

        // P -> LDS bf16 (per-wave region; same-wave write->read)
        #pragma unroll
        for (int t4 = 0; t4 < 4; ++t4)
            #pragma unroll
            for (int pr = 0; pr < 2; ++pr) {
                unsigned u = (unsigned)f2bf(sacc[t4][2 * pr]) |
                             ((unsigned)f2bf(sacc[t4][2 * pr + 1]) << 16);
                unsigned byte = pbase + ((unsigned)sl << 7) + (unsigned)(t4 * 32 + tg * 8 + pr * 4);
                byte ^= (unsigned)((sl & 7) << 4);
                *reinterpret_cast<unsigned*>(smP + byte) = u;
            }

        // PV: acc[s][d] += P[s][t] V[t][d]
        #pragma unroll
        for (int ks = 0; ks < 2; ++ks) {
            unsigned pbyte = pbase + ((unsigned)sl << 7) + (unsigned)(ks << 6) + (unsigned)(tg << 4);
            pbyte ^= (unsigned)((sl & 7) << 4);
            bf16x8 pf = *reinterpret_cast<const bf16x8*>(smP + pbyte);
            #pragma unroll
            for (int dt = 0; dt < 4; ++dt) {
                int d = dt * 16 + sl;
                unsigned vbyte = ((unsigned)d << 7) + (unsigned)(ks << 6) + (unsigned)(tg << 4);
                vbyte ^= (unsigned)((d & 7) << 4);
                bf16x8 vf = *reinterpret_cast<const bf16x8*>(vbase + vbyte);
                acc_pv[dt] = __builtin_amdgcn_mfma_f32_16x16x32_bf16(pf, vf, acc_pv[dt], 0, 0, 0);
            }
        }
    }

    // es: per-lane partial over its t-quarter -> full row sum (within group)
    #pragma unroll
    for (int r2 = 0; r2 < NREL; ++r2) {
        es[r2] += __shfl_xor(es[r2], 16);
        es[r2] += __shfl_xor(es[r2], 32);
    }

    // ---- publish partials & merge the two t-groups ----
    __syncthreads();   // K/V LDS no longer needed; safe to reuse
    float* accL  = reinterpret_cast<float*>(smK);    // [64 rows][64 d]
    float* stats = reinterpret_cast<float*>(smVt);   // m[2][64], l[2][64], es[2][3][64]

    if (tg == 0) {
        stats[tgroup * 64 + srow]        = m_run;
        stats[128 + tgroup * 64 + srow]  = l_run;
        #pragma unroll
        for (int r2 = 0; r2 < NREL; ++r2)
            stats[256 + (tgroup * 3 + r2) * 64 + srow] = es[r2];
    }
    if (tgroup == 1) {
        #pragma unroll
        for (int dt = 0; dt < 4; ++dt)
            #pragma unroll
            for (int r = 0; r < 4; ++r)
                accL[(qstrip * 16 + tg * 4 + r) * 64 + dt * 16 + sl] = acc_pv[dt][r];
    }
    __syncthreads();

    if (tgroup == 0) {
        unsigned short* dst = ob + ((size_t)(b * S_LEN + s0 + qstrip * 16)) * EMB + h * DPH;
        #pragma unroll
        for (int r = 0; r < 4; ++r) {
            const int row64 = qstrip * 16 + tg * 4 + r;
            float m0 = stats[row64],        m1 = stats[64 + row64];
            float l0 = stats[128 + row64],  l1 = stats[192 + row64];
            float mm = fmaxf(m0, m1);
            float a0 = __expf(m0 - mm), a1 = __expf(m1 - mm);
            float linv = 1.f / (a0 * l0 + a1 * l1);
            float e0 = a0 * stats[256 + 0 * 64 + row64] + a1 * stats[256 + 3 * 64 + row64];
            float e1 = a0 * stats[256 + 1 * 64 + row64] + a1 * stats[256 + 4 * 64 + row64];
            float e2 = a0 * stats[256 + 2 * 64 + row64] + a1 * stats[256 + 5 * 64 + row64];
            #pragma unroll
            for (int dt = 0; dt < 4; ++dt) {
                int d = dt * 16 + sl;
                float o = a0 * acc_pv[dt][r] + a1 * accL[row64 * 64 + d];
                o += e0 * relv_s[0][d] + e1 * relv_s[1][d] + e2 * relv_s[2][d];
                o *= linv;
                dst[(size_t)(tg * 4 + r) * EMB + d] = f2bf(o);
            }
        }
    }
}

extern "C" void kernel_launch(void* const* d_in, const int* in_sizes, int n_in,
                              void* d_out, int out_size, void* d_ws, size_t ws_size,
                              hipStream_t stream) {
    int iq=0, ik=1, iv=2, irel=3, iWq=4, ibq=5, iWk=6, ibk=7, iWv=8, ibv=9, iWo=10, ibo=11, irk=12, irv=13;
    if (n_in >= 14 && in_sizes[0] == 512 * 512) {
        iWk=0; iWo=1; iWq=2; iWv=3; ibk=4; ibo=5; ibq=6; ibv=7;
        irel=8; ik=9; iq=10; irk=11; irv=12; iv=13;
    }

    const float* q_in = (const float*)d_in[iq];
    const float* k_in = (const float*)d_in[ik];
    const float* v_in = (const float*)d_in[iv];
    const int*   grel = (const int*)d_in[irel];
    const float* Wq = (const float*)d_in[iWq];
    const float* bq = (const float*)d_in[ibq];
    const float* Wk = (const float*)d_in[iWk];
    const float* bk = (const float*)d_in[ibk];
    const float* Wv = (const float*)d_in[iWv];
    const float* bv = (const float*)d_in[ibv];
    const float* Wo = (const float*)d_in[iWo];
    const float* bo = (const float*)d_in[ibo];
    const float* rk = (const float*)d_in[irk];
    const float* rv = (const float*)d_in[irv];

    unsigned short* qb  = (unsigned short*)d_ws;
    unsigned short* kb  = qb + (size_t)4096 * 512;
    unsigned short* vbT = kb + (size_t)4096 * 512;   // [b*NHEAD+h][d][s]
    unsigned short* ab  = vbT + (size_t)4096 * 512;
    unsigned short* wt  = ab + (size_t)4096 * 512;

    dim3 blk(256);
    transpose_w<<<dim3(8, 8, 4), blk, 0, stream>>>(Wq, Wk, Wv, Wo, wt);
    gemm_proj_mfma<<<dim3(8, 32, 3), blk, 0, stream>>>(q_in, k_in, v_in, wt, bq, bk, bv, qb, kb, vbT);
    attn_mfma<<<dim3(8, NHEAD, BATCH), dim3(512), 0, stream>>>(qb, kb, vbT, grel, rk, rv, ab);
    gemm_out_mfma<<<dim3(8, 32), blk, 0, stream>>>(ab, wt + (size_t)3 * 512 * 512, bo, (float*)d_out);
}